// Round 8
// baseline (1411.313 us; speedup 1.0000x reference)
//
#include <hip/hip_runtime.h>

#define N_ROWS 32768
#define NEMB   4096
#define DIM    256

// output layout (flat float32)
#define O_LOSS 0
#define O_ZQ   1ull
#define O_PERP 8388609ull
#define O_ENC  8388610ull
#define O_IDX  142606338ull
// min_encodings zero region, float4-aligned interior [8388612, 142606336)
#define Z4_BEG 2097153
#define Z4_END 35651584

#define CAP    32        // per-row candidate list capacity
#define EPS    1e-3f     // bf16 filter margin (needs > ~6e-4; proven passing)

typedef unsigned long long u64;
typedef __attribute__((ext_vector_type(8))) __bf16 bf16x8;
typedef __attribute__((ext_vector_type(4))) float  f32x4;

// workspace layout (unchanged)
// [0, 512KB)          u64 ws_best[32768][2]
// [1048576, +16KB)    int counts[4096]
// [1064960, +16KB)    double parts[2048]  (1024 used)
// [1081344, +128KB)   int ws_idx[32768]
//
// bf16 scratch inside z_q output region (overwritten later by vq_zq):
//   zbf  : z as bf16 row-major [32768][256] (16 MB) at out+16B
//   embsw: emb bf16, 16B-chunk XOR-swizzled (chunk ^= code&7) per 512B row (2 MB)

__device__ __forceinline__ unsigned int f2bf1(float x) {
    unsigned int u = __float_as_uint(x);
    return (u + 0x7fffu + ((u >> 16) & 1u)) >> 16;
}
__device__ __forceinline__ unsigned int f2bf2(float lo, float hi) {
    return f2bf1(lo) | (f2bf1(hi) << 16);
}

// ---------------------------------------------------------------------------
// K0: one-time prep (validated, unchanged).
// ---------------------------------------------------------------------------
__global__ __launch_bounds__(256)
void vq_prep(const float* __restrict__ z, const float* __restrict__ emb,
             unsigned short* __restrict__ zbf, unsigned short* __restrict__ embsw,
             int* __restrict__ counts, float* __restrict__ out)
{
    const int tid = threadIdx.x, blk = blockIdx.x;
    if (blk < 1024) {
        __shared__ float L[32][256];
        const int b = blk >> 5, sub = blk & 31;
        const int c0 = (sub >> 2) << 5;
        const int hw0 = (sub & 3) << 8;
        const float* zp = z + (size_t)b * 262144 + hw0 + tid;
#pragma unroll 8
        for (int i = 0; i < 32; ++i)
            L[i][tid] = zp[(size_t)(c0 + i) << 10];
        __syncthreads();
        const int n = (b << 10) + hw0 + tid;
        unsigned int pk[16];
#pragma unroll
        for (int c2 = 0; c2 < 16; ++c2)
            pk[c2] = f2bf2(L[2 * c2][tid], L[2 * c2 + 1][tid]);
        uint4* dst = (uint4*)((char*)zbf + (size_t)n * 512 + (size_t)c0 * 2);
#pragma unroll
        for (int q = 0; q < 4; ++q)
            dst[q] = make_uint4(pk[4*q], pk[4*q+1], pk[4*q+2], pk[4*q+3]);
    } else {
        const int base = ((blk - 1024) << 8) + tid;
#pragma unroll
        for (int q = 0; q < 4; ++q) {
            const int ch = (base << 2) + q;
            const int code = ch >> 5, cw = ch & 31;
            const float* ep = emb + (size_t)code * 256 + cw * 8;
            float4 e0 = *(const float4*)ep;
            float4 e1 = *(const float4*)(ep + 4);
            uint4 pk = make_uint4(f2bf2(e0.x, e0.y), f2bf2(e0.z, e0.w),
                                  f2bf2(e1.x, e1.y), f2bf2(e1.z, e1.w));
            *(uint4*)((char*)embsw + (size_t)code * 512 + (size_t)((cw ^ (code & 7)) << 4)) = pk;
        }
        if (blk == 1024) {
            for (int j = tid; j < NEMB; j += 256) counts[j] = 0;
            if (tid == 0) {
                out[O_ENC] = 0.f; out[O_ENC + 1] = 0.f;
                out[(size_t)Z4_END * 4] = 0.f; out[(size_t)Z4_END * 4 + 1] = 0.f;
            }
        }
    }
}

// ---------------------------------------------------------------------------
// K1: SINGLE-PASS bf16-MFMA filter (online threshold) at the VALIDATED R1
// tiling: grid 256 = 128 row-blocks x 2 code-halves, 512 thr = 8 waves x
// 32 rows, 64-code tiles, lockstep __syncthreads double buffer, fused
// zero-fill (now 8 float4/thread/step since steps halved 64->32; total
// store volume unchanged). Online threshold: runmax_t <= max_final, so
// every two-pass candidate is recorded (superset); exact fmaf-chain rescore
// + overflow fallback => selection provably identical (validated R3/R4/R6).
// ---------------------------------------------------------------------------
__global__ __launch_bounds__(512, 2)
void vq_filter(const float* __restrict__ z, const float* __restrict__ emb,
               const unsigned short* __restrict__ zbf_us,
               const unsigned short* __restrict__ embsw,
               float* __restrict__ out, u64* __restrict__ ws_best)
{
#pragma clang fp contract(off)
    __shared__ __align__(16) char Bsh[65536];     // 2 x (64 codes x 256 k) bf16
    __shared__ float zsumS[256];
    __shared__ unsigned short rowlist[256][CAP];
    __shared__ int rowcnt[256];
    __shared__ int nflag;
    __shared__ int flagrows[32];
    __shared__ u64 flagbest[32];

    const int tid = threadIdx.x;
    const int blk = blockIdx.x;
    const int rb  = blk >> 1;            // row-block 0..127 (256 rows each)
    const int hv  = blk & 1;             // code half
    const int n0  = rb << 8;
    const int C0  = hv << 11;
    const int b   = n0 >> 10;
    const int hw0 = n0 & 1023;
    const int w    = tid >> 6;
    const int lane = tid & 63;
    const int r0w  = w << 5;             // wave's 32-row base
    const int arow = lane & 15;
    const int akg  = lane >> 4;
    const float* zb = z + (size_t)b * 262144 + hw0;

    if (tid < 32) flagbest[tid] = ~0ull;
    if (tid == 0) nflag = 0;

    // ---- zsum: numpy pairwise_sum replica (verbatim numerics) ----
    if (tid < 256) {
        rowcnt[tid] = 0;
        const float* gz = zb + tid;
        float hs0, hs1;
        {
            float r[8];
#pragma unroll
            for (int j = 0; j < 8; ++j) { float v = gz[(size_t)j << 10]; r[j] = v * v; }
            for (int m = 1; m < 16; ++m)
#pragma unroll
                for (int j = 0; j < 8; ++j) {
                    float v = gz[(size_t)(8 * m + j) << 10];
                    float sq = v * v;
                    r[j] = r[j] + sq;
                }
            hs0 = ((r[0] + r[1]) + (r[2] + r[3])) + ((r[4] + r[5]) + (r[6] + r[7]));
        }
        {
            float r[8];
#pragma unroll
            for (int j = 0; j < 8; ++j) { float v = gz[(size_t)(128 + j) << 10]; r[j] = v * v; }
            for (int m = 1; m < 16; ++m)
#pragma unroll
                for (int j = 0; j < 8; ++j) {
                    float v = gz[(size_t)(128 + 8 * m + j) << 10];
                    float sq = v * v;
                    r[j] = r[j] + sq;
                }
            hs1 = ((r[0] + r[1]) + (r[2] + r[3])) + ((r[4] + r[5]) + (r[6] + r[7]));
        }
        zsumS[tid] = hs0 + hs1;
    }

    // ---- A fragments: wave's 32 rows x full K=256, bf16, in registers ----
    bf16x8 A[2][8];
#pragma unroll
    for (int rf = 0; rf < 2; ++rf)
#pragma unroll
        for (int s = 0; s < 8; ++s)
            A[rf][s] = *(const bf16x8*)((const char*)zbf_us
                        + ((size_t)(n0 + r0w + rf * 16 + arow) << 9)
                        + (size_t)((s * 32 + akg * 8) << 1));

    // B-tile staging: linear global_load_lds (source is pre-swizzled)
    auto stage = [&](int buf, int ct) {
        const char* sb = (const char*)embsw + (((size_t)(C0 + (ct << 6))) << 9)
                         + (w << 10) + (lane << 4);
        char* db = Bsh + buf * 32768 + (w << 10);
#pragma unroll
        for (int it = 0; it < 4; ++it) {
            __builtin_amdgcn_global_load_lds(
                (const __attribute__((address_space(1))) unsigned int*)(sb + it * 8192),
                (__attribute__((address_space(3))) unsigned int*)(db + it * 8192),
                16, 0, 0);
        }
    };

    float runmax[2][4];
#pragma unroll
    for (int rf = 0; rf < 2; ++rf)
#pragma unroll
        for (int j = 0; j < 4; ++j) runmax[rf][j] = -3.4e38f;

    const size_t zf_base = (size_t)Z4_BEG + (size_t)blk * 131072;

    stage(0, 0);
    __syncthreads();                       // drains vmcnt -> buf0 ready

    for (int ct = 0; ct < 32; ++ct) {
        const int buf = ct & 1;
        if (ct < 31) stage(buf ^ 1, ct + 1);

        // fused zero-fill of min_encodings (8 coalesced float4/thread/tile)
        {
            const size_t g = zf_base + (size_t)ct * 4096 + tid;
            const float4 zv = make_float4(0.f, 0.f, 0.f, 0.f);
#pragma unroll
            for (int q = 0; q < 8; ++q) {
                const size_t i4 = g + (size_t)q * 512;
                if (i4 < (size_t)Z4_END) ((float4*)out)[i4] = zv;
            }
        }

        f32x4 acc[2][4];
        const f32x4 zz = {0.f, 0.f, 0.f, 0.f};
#pragma unroll
        for (int rf = 0; rf < 2; ++rf)
#pragma unroll
            for (int cf = 0; cf < 4; ++cf) acc[rf][cf] = zz;

        const char* bufp = Bsh + buf * 32768;
#pragma unroll
        for (int s = 0; s < 8; ++s) {
#pragma unroll
            for (int cf = 0; cf < 4; ++cf) {
                const int cl = (cf << 4) + arow;
                const int off = (cl << 9) + (((s << 6) + (akg << 4)) ^ ((cl & 7) << 4));
                bf16x8 bb = *(const bf16x8*)(bufp + off);
                acc[0][cf] = __builtin_amdgcn_mfma_f32_16x16x32_bf16(A[0][s], bb, acc[0][cf], 0, 0, 0);
                acc[1][cf] = __builtin_amdgcn_mfma_f32_16x16x32_bf16(A[1][s], bb, acc[1][cf], 0, 0, 0);
            }
        }

        // ---- online threshold + record (every step) ----
#pragma unroll
        for (int rf = 0; rf < 2; ++rf) {
#pragma unroll
            for (int j = 0; j < 4; ++j) {
                float m = fmaxf(fmaxf(acc[rf][0][j], acc[rf][1][j]),
                                fmaxf(acc[rf][2][j], acc[rf][3][j]));
                m = fmaxf(m, __shfl_xor(m, 1));
                m = fmaxf(m, __shfl_xor(m, 2));
                m = fmaxf(m, __shfl_xor(m, 4));
                m = fmaxf(m, __shfl_xor(m, 8));
                const float rm = fmaxf(runmax[rf][j], m);
                runmax[rf][j] = rm;
                const float th = rm - EPS;
#pragma unroll
                for (int cf = 0; cf < 4; ++cf) {
                    if (acc[rf][cf][j] >= th) {
                        const int row  = r0w + rf * 16 + akg * 4 + j;
                        const int code = (ct << 6) + (cf << 4) + arow;
                        const int slot = atomicAdd(&rowcnt[row], 1);
                        if (slot < CAP) rowlist[row][slot] = (unsigned short)code;
                        else if (slot == CAP) {
                            const int fi = atomicAdd(&nflag, 1);
                            if (fi < 32) flagrows[fi] = row;
                        }
                    }
                }
            }
        }
        __syncthreads();                   // next buf staged; all waves done reading
    }
    __syncthreads();

    // ---- exact rescore of recorded candidates (validated fmaf-chain) ----
    if (tid < 256) {
        const int cnt = rowcnt[tid];
        if (cnt <= CAP) {                  // cnt >= 1 always (argmax records itself)
            const float zs = zsumS[tid];
            const float* zrow = zb + tid;
            u64 bestk = ~0ull;
            for (int basec = 0; basec < cnt; basec += 8) {
                int codes[8];
#pragma unroll
                for (int j = 0; j < 8; ++j) {
                    const int jj = basec + j;
                    codes[j] = rowlist[tid][jj < cnt ? jj : basec];
                }
                const float* ep[8];
#pragma unroll
                for (int j = 0; j < 8; ++j) ep[j] = emb + ((size_t)(C0 + codes[j]) << 8);
                float a8[8] = {0.f, 0.f, 0.f, 0.f, 0.f, 0.f, 0.f, 0.f};
#pragma unroll 2
                for (int k4 = 0; k4 < 64; ++k4) {
                    const float zv0 = zrow[(size_t)(4 * k4 + 0) << 10];
                    const float zv1 = zrow[(size_t)(4 * k4 + 1) << 10];
                    const float zv2 = zrow[(size_t)(4 * k4 + 2) << 10];
                    const float zv3 = zrow[(size_t)(4 * k4 + 3) << 10];
                    float4 e4[8];
#pragma unroll
                    for (int j = 0; j < 8; ++j) e4[j] = *(const float4*)(ep[j] + 4 * k4);
#pragma unroll
                    for (int j = 0; j < 8; ++j) {
                        a8[j] = fmaf(zv0, e4[j].x, a8[j]);
                        a8[j] = fmaf(zv1, e4[j].y, a8[j]);
                        a8[j] = fmaf(zv2, e4[j].z, a8[j]);
                        a8[j] = fmaf(zv3, e4[j].w, a8[j]);
                    }
                }
#pragma unroll
                for (int j = 0; j < 8; ++j) {
                    if (basec + j < cnt) {
                        const float d = fmaf(-2.f, a8[j], zs);
                        const u64 key = ((u64)__float_as_uint(d) << 32)
                                      | (unsigned)(C0 + codes[j]);
                        if (key < bestk) bestk = key;
                    }
                }
            }
            ws_best[((size_t)(n0 + tid) << 1) + hv] = bestk;
        }
    }
    __syncthreads();

    // ---- overflow fallback: full exact scan for flagged rows (rare) ----
    const int nf = (nflag > 32) ? 32 : nflag;
    for (int f = 0; f < nf; ++f) {
        const int fr = flagrows[f];
        if (tid < 256) {
            const float zs = zsumS[fr];
            const float* zrow = zb + fr;
            const float* ep0 = emb + ((size_t)(C0 + (tid << 3)) << 8);
            float a8[8] = {0.f, 0.f, 0.f, 0.f, 0.f, 0.f, 0.f, 0.f};
#pragma unroll 2
            for (int k4 = 0; k4 < 64; ++k4) {
                const float zv0 = zrow[(size_t)(4 * k4 + 0) << 10];
                const float zv1 = zrow[(size_t)(4 * k4 + 1) << 10];
                const float zv2 = zrow[(size_t)(4 * k4 + 2) << 10];
                const float zv3 = zrow[(size_t)(4 * k4 + 3) << 10];
#pragma unroll
                for (int j = 0; j < 8; ++j) {
                    const float4 e4 = *(const float4*)(ep0 + (size_t)j * 256 + 4 * k4);
                    a8[j] = fmaf(zv0, e4.x, a8[j]);
                    a8[j] = fmaf(zv1, e4.y, a8[j]);
                    a8[j] = fmaf(zv2, e4.z, a8[j]);
                    a8[j] = fmaf(zv3, e4.w, a8[j]);
                }
            }
            u64 bk = ~0ull;
#pragma unroll
            for (int j = 0; j < 8; ++j) {
                const float d = fmaf(-2.f, a8[j], zs);
                const u64 key = ((u64)__float_as_uint(d) << 32)
                              | (unsigned)(C0 + (tid << 3) + j);
                if (key < bk) bk = key;
            }
            atomicMin(&flagbest[f], bk);
        }
    }
    __syncthreads();
    if (tid < nf) ws_best[((size_t)(n0 + flagrows[tid]) << 1) + hv] = flagbest[tid];
}

// ---------------------------------------------------------------------------
// K2: reduce 2 candidates/row, write idx output, one-hot ones, histogram.
// ---------------------------------------------------------------------------
__global__ void vq_scatter(const u64* __restrict__ ws_best, float* __restrict__ out,
                           int* __restrict__ counts, int* __restrict__ ws_idx)
{
    int i = blockIdx.x * 256 + threadIdx.x;
    if (i < N_ROWS) {
        u64 m = ws_best[(size_t)i * 2];
        u64 v = ws_best[(size_t)i * 2 + 1];
        if (v < m) m = v;
        int id = (int)(m & 0xffffffffu);
        ws_idx[i] = id;
        out[O_IDX + i] = (float)id;
        out[O_ENC + (size_t)i * 4096 + id] = 1.0f;
        atomicAdd(&counts[id], 1);
    }
}

// ---------------------------------------------------------------------------
// K3: z_q + per-block loss partials (validated R6/R7 LDS-staged version).
// ---------------------------------------------------------------------------
__global__ __launch_bounds__(256)
void vq_zq(const float* __restrict__ z, const float* __restrict__ emb,
           const int* __restrict__ ws_idx, float* __restrict__ out,
           double* __restrict__ parts)
{
#pragma clang fp contract(off)
    __shared__ float embT[32][257];
    __shared__ int idxS[32];
    __shared__ double red[256];

    const int tid = threadIdx.x;
    const int blk = blockIdx.x;            // 0..1023
    const int b   = blk >> 5;              // batch
    const int hw0 = (blk & 31) << 5;       // 32-row chunk
    const int n0  = (b << 10) + hw0;

    if (tid < 32) idxS[tid] = ws_idx[n0 + tid];
    __syncthreads();

    {   // fill: group g stages emb row idxS[g]; 8 lanes x 8 float4 iters
        const int g = tid >> 3, l8 = tid & 7;
        const float* er = emb + (size_t)idxS[g] * 256;
#pragma unroll
        for (int it = 0; it < 8; ++it) {
            const float4 v = *(const float4*)(er + it * 32 + l8 * 4);
            const int c = it * 32 + l8 * 4;
            embT[g][c]     = v.x;
            embT[g][c + 1] = v.y;
            embT[g][c + 2] = v.z;
            embT[g][c + 3] = v.w;
        }
    }
    __syncthreads();

    const int r  = tid & 31;
    const int cq = tid >> 5;
    const size_t base = (size_t)b * 262144 + hw0 + r;
    double val = 0.0;
#pragma unroll 4
    for (int i = 0; i < 32; ++i) {
        const int c = i * 8 + cq;
        const size_t gid = base + (size_t)c * 1024;
        const float zp = z[gid];
        const float e  = embT[r][c];
        const float t  = e - zp;
        const float zq = zp + t;
        __builtin_nontemporal_store(zq, &out[O_ZQ + gid]);
        const float diff = zq - zp;
        val += (double)(diff * diff);
    }

    red[tid] = val;
    __syncthreads();
    for (int st = 128; st > 0; st >>= 1) {
        if (tid < st) red[tid] += red[tid + st];
        __syncthreads();
    }
    if (tid == 0) parts[blk] = red[0];
}

// ---------------------------------------------------------------------------
// K4: finalize loss and perplexity (1024 parts).
// ---------------------------------------------------------------------------
__global__ void vq_final(const int* __restrict__ counts,
                         const double* __restrict__ parts, float* __restrict__ out)
{
    __shared__ double red[256];
    const int t = threadIdx.x;

    double loc = 0.0;
    for (int j = t; j < NEMB; j += 256) {
        float em = (float)counts[j] * (1.0f / 32768.0f);
        float lt = em + 1e-10f;
        float lg = logf(lt);
        float pr = em * lg;
        loc += (double)pr;
    }
    red[t] = loc;
    __syncthreads();
    for (int st = 128; st > 0; st >>= 1) {
        if (t < st) red[t] += red[t + st];
        __syncthreads();
    }
    double s = red[0];
    __syncthreads();

    double q = 0.0;
    for (int j = t; j < 1024; j += 256) q += parts[j];
    red[t] = q;
    __syncthreads();
    for (int st = 128; st > 0; st >>= 1) {
        if (t < st) red[t] += red[t + st];
        __syncthreads();
    }
    if (t == 0) {
        out[O_PERP] = expf(-(float)s);
        double qm = red[0] * (1.0 / 8388608.0);
        float  qf = (float)qm;
        out[O_LOSS] = qf + 0.25f * qf;
    }
}

extern "C" void kernel_launch(void* const* d_in, const int* in_sizes, int n_in,
                              void* d_out, int out_size, void* d_ws, size_t ws_size,
                              hipStream_t stream)
{
    const float* z   = (const float*)d_in[0];
    const float* emb = (const float*)d_in[1];
    float* out = (float*)d_out;

    u64*    ws_best = (u64*)d_ws;
    int*    counts  = (int*)((char*)d_ws + 1048576);
    double* parts   = (double*)((char*)d_ws + 1064960);
    int*    ws_idx  = (int*)((char*)d_ws + 1081344);

    unsigned short* zbf   = (unsigned short*)((char*)d_out + 16);
    unsigned short* embsw = (unsigned short*)((char*)d_out + 16 + 16777216);

    vq_prep   <<<1152, 256, 0, stream>>>(z, emb, zbf, embsw, counts, out);
    vq_filter <<<256,  512, 0, stream>>>(z, emb, zbf, embsw, out, ws_best);
    vq_scatter<<<128,  256, 0, stream>>>(ws_best, out, counts, ws_idx);
    vq_zq     <<<1024, 256, 0, stream>>>(z, emb, ws_idx, out, parts);
    vq_final  <<<1,    256, 0, stream>>>(counts, parts, out);
}

// Round 9
// 1186.779 us; speedup vs baseline: 1.1892x; 1.1892x over previous
//
#include <hip/hip_runtime.h>

#define N_ROWS 32768
#define NEMB   4096
#define DIM    256

// output layout (flat float32)
#define O_LOSS 0
#define O_ZQ   1ull
#define O_PERP 8388609ull
#define O_ENC  8388610ull
#define O_IDX  142606338ull
// min_encodings zero region, float4-aligned interior [8388612, 142606336)
#define Z4_BEG 2097153
#define Z4_END 35651584

#define CAP    16        // per-row candidate list capacity (two-pass avg ~5;
                         // P(cnt>16) ~ 6e-6/row-half; fallback handles overflow)
#define EPS    1e-3f     // bf16 filter margin (needs > ~6e-4; proven passing)

typedef unsigned long long u64;
typedef __attribute__((ext_vector_type(8))) __bf16 bf16x8;
typedef __attribute__((ext_vector_type(4))) float  f32x4;

// workspace layout
// [0, 512KB)          u64 ws_best[32768][2]
// [1048576, +16KB)    int counts[4096]
// [1064960, +16KB)    double parts[2048]  (1024 used)
//
// bf16 scratch inside z_q output region (overwritten later by vq_zq):
//   zbf  : z as bf16 row-major [32768][256] (16 MB) at out+16B
//   embsw: emb bf16, 16B-chunk XOR-swizzled (chunk ^= code&7) per 512B row (2 MB)

__device__ __forceinline__ unsigned int f2bf1(float x) {
    unsigned int u = __float_as_uint(x);
    return (u + 0x7fffu + ((u >> 16) & 1u)) >> 16;
}
__device__ __forceinline__ unsigned int f2bf2(float lo, float hi) {
    return f2bf1(lo) | (f2bf1(hi) << 16);
}

// ---------------------------------------------------------------------------
// K0: one-time prep (validated, unchanged).
// ---------------------------------------------------------------------------
__global__ __launch_bounds__(256)
void vq_prep(const float* __restrict__ z, const float* __restrict__ emb,
             unsigned short* __restrict__ zbf, unsigned short* __restrict__ embsw,
             int* __restrict__ counts, float* __restrict__ out)
{
    const int tid = threadIdx.x, blk = blockIdx.x;
    if (blk < 1024) {
        __shared__ float L[32][256];
        const int b = blk >> 5, sub = blk & 31;
        const int c0 = (sub >> 2) << 5;
        const int hw0 = (sub & 3) << 8;
        const float* zp = z + (size_t)b * 262144 + hw0 + tid;
#pragma unroll 8
        for (int i = 0; i < 32; ++i)
            L[i][tid] = zp[(size_t)(c0 + i) << 10];
        __syncthreads();
        const int n = (b << 10) + hw0 + tid;
        unsigned int pk[16];
#pragma unroll
        for (int c2 = 0; c2 < 16; ++c2)
            pk[c2] = f2bf2(L[2 * c2][tid], L[2 * c2 + 1][tid]);
        uint4* dst = (uint4*)((char*)zbf + (size_t)n * 512 + (size_t)c0 * 2);
#pragma unroll
        for (int q = 0; q < 4; ++q)
            dst[q] = make_uint4(pk[4*q], pk[4*q+1], pk[4*q+2], pk[4*q+3]);
    } else {
        const int base = ((blk - 1024) << 8) + tid;
#pragma unroll
        for (int q = 0; q < 4; ++q) {
            const int ch = (base << 2) + q;
            const int code = ch >> 5, cw = ch & 31;
            const float* ep = emb + (size_t)code * 256 + cw * 8;
            float4 e0 = *(const float4*)ep;
            float4 e1 = *(const float4*)(ep + 4);
            uint4 pk = make_uint4(f2bf2(e0.x, e0.y), f2bf2(e0.z, e0.w),
                                  f2bf2(e1.x, e1.y), f2bf2(e1.z, e1.w));
            *(uint4*)((char*)embsw + (size_t)code * 512 + (size_t)((cw ^ (code & 7)) << 4)) = pk;
        }
        if (blk == 1024) {
            for (int j = tid; j < NEMB; j += 256) counts[j] = 0;
            if (tid == 0) {
                out[O_ENC] = 0.f; out[O_ENC + 1] = 0.f;
                out[(size_t)Z4_END * 4] = 0.f; out[(size_t)Z4_END * 4 + 1] = 0.f;
            }
        }
    }
}

// ---------------------------------------------------------------------------
// K1: bf16-MFMA filter + exact-fp32 rescore — FROZEN R1/R7 two-pass lockstep
// structure (4 deviations failed: R2/R4 async, R6 retile, R8 single-pass).
// This round changes ONLY: (a) fused zero-fill stores -> nontemporal (stop
// L2 write-allocate evicting embsw/emb: R1 FETCH 141MB >> ~40MB logical);
// (b) CAP 32->16 -> LDS 77.2KB -> 2 blocks/CU (block B computes while block
// A drains its barrier). grid 256 = 128 row-blocks x 2 code-halves.
// ---------------------------------------------------------------------------
__global__ __launch_bounds__(512, 2)
void vq_filter(const float* __restrict__ z, const float* __restrict__ emb,
               const unsigned short* __restrict__ zbf_us,
               const unsigned short* __restrict__ embsw,
               float* __restrict__ out, u64* __restrict__ ws_best)
{
#pragma clang fp contract(off)
    __shared__ __align__(16) char Bsh[65536];     // 2 x (64 codes x 256 k) bf16
    __shared__ float zsumS[256];
    __shared__ float rowmaxS[256];
    __shared__ unsigned short rowlist[256][CAP];
    __shared__ int rowcnt[256];
    __shared__ int nflag;
    __shared__ int flagrows[32];
    __shared__ u64 flagbest[32];

    const int tid = threadIdx.x;
    const int blk = blockIdx.x;
    const int rb  = blk >> 1;            // row-block 0..127 (256 rows each)
    const int hv  = blk & 1;             // code half
    const int n0  = rb << 8;
    const int C0  = hv << 11;
    const int b   = n0 >> 10;
    const int hw0 = n0 & 1023;
    const int w    = tid >> 6;
    const int lane = tid & 63;
    const int r0w  = w << 5;             // wave's 32-row base
    const int arow = lane & 15;
    const int akg  = lane >> 4;
    const float* zb = z + (size_t)b * 262144 + hw0;

    if (tid < 32) flagbest[tid] = ~0ull;
    if (tid == 0) nflag = 0;

    // ---- zsum: numpy pairwise_sum replica (verbatim numerics) ----
    if (tid < 256) {
        rowcnt[tid] = 0;
        const float* gz = zb + tid;
        float hs0, hs1;
        {
            float r[8];
#pragma unroll
            for (int j = 0; j < 8; ++j) { float v = gz[(size_t)j << 10]; r[j] = v * v; }
            for (int m = 1; m < 16; ++m)
#pragma unroll
                for (int j = 0; j < 8; ++j) {
                    float v = gz[(size_t)(8 * m + j) << 10];
                    float sq = v * v;
                    r[j] = r[j] + sq;
                }
            hs0 = ((r[0] + r[1]) + (r[2] + r[3])) + ((r[4] + r[5]) + (r[6] + r[7]));
        }
        {
            float r[8];
#pragma unroll
            for (int j = 0; j < 8; ++j) { float v = gz[(size_t)(128 + j) << 10]; r[j] = v * v; }
            for (int m = 1; m < 16; ++m)
#pragma unroll
                for (int j = 0; j < 8; ++j) {
                    float v = gz[(size_t)(128 + 8 * m + j) << 10];
                    float sq = v * v;
                    r[j] = r[j] + sq;
                }
            hs1 = ((r[0] + r[1]) + (r[2] + r[3])) + ((r[4] + r[5]) + (r[6] + r[7]));
        }
        zsumS[tid] = hs0 + hs1;
    }

    // ---- A fragments: wave's 32 rows x full K=256, bf16, in registers ----
    bf16x8 A[2][8];
#pragma unroll
    for (int rf = 0; rf < 2; ++rf)
#pragma unroll
        for (int s = 0; s < 8; ++s)
            A[rf][s] = *(const bf16x8*)((const char*)zbf_us
                        + ((size_t)(n0 + r0w + rf * 16 + arow) << 9)
                        + (size_t)((s * 32 + akg * 8) << 1));

    // B-tile staging: linear global_load_lds (source is pre-swizzled)
    auto stage = [&](int buf, int ct) {
        const char* sb = (const char*)embsw + (((size_t)(C0 + (ct << 6))) << 9)
                         + (w << 10) + (lane << 4);
        char* db = Bsh + buf * 32768 + (w << 10);
#pragma unroll
        for (int it = 0; it < 4; ++it) {
            __builtin_amdgcn_global_load_lds(
                (const __attribute__((address_space(1))) unsigned int*)(sb + it * 8192),
                (__attribute__((address_space(3))) unsigned int*)(db + it * 8192),
                16, 0, 0);
        }
    };

    float vmax[2][4];
#pragma unroll
    for (int rf = 0; rf < 2; ++rf)
#pragma unroll
        for (int j = 0; j < 4; ++j) vmax[rf][j] = -3.4e38f;
    float thr[2][4];

    const size_t zf_base = (size_t)Z4_BEG + (size_t)blk * 131072;
    const f32x4 zntv = {0.f, 0.f, 0.f, 0.f};

    for (int pass = 0; pass < 2; ++pass) {
        stage(0, 0);
        __syncthreads();                       // drains vmcnt -> buf0 ready
        for (int ct = 0; ct < 32; ++ct) {
            const int buf = ct & 1;
            if (ct < 31) stage(buf ^ 1, ct + 1);

            // fused zero-fill of min_encodings (4 coalesced nt float4/thread)
            {
                const int iter = pass * 32 + ct;
                const size_t g = zf_base + (size_t)iter * 2048 + tid;
#pragma unroll
                for (int q = 0; q < 4; ++q) {
                    const size_t i4 = g + (size_t)q * 512;
                    if (i4 < (size_t)Z4_END)
                        __builtin_nontemporal_store(zntv, (f32x4*)out + i4);
                }
            }

            f32x4 acc[2][4];
            const f32x4 zz = {0.f, 0.f, 0.f, 0.f};
#pragma unroll
            for (int rf = 0; rf < 2; ++rf)
#pragma unroll
                for (int cf = 0; cf < 4; ++cf) acc[rf][cf] = zz;

            const char* bufp = Bsh + buf * 32768;
#pragma unroll
            for (int s = 0; s < 8; ++s) {
#pragma unroll
                for (int cf = 0; cf < 4; ++cf) {
                    const int cl = (cf << 4) + arow;
                    const int off = (cl << 9) + (((s << 6) + (akg << 4)) ^ ((cl & 7) << 4));
                    bf16x8 bb = *(const bf16x8*)(bufp + off);
                    acc[0][cf] = __builtin_amdgcn_mfma_f32_16x16x32_bf16(A[0][s], bb, acc[0][cf], 0, 0, 0);
                    acc[1][cf] = __builtin_amdgcn_mfma_f32_16x16x32_bf16(A[1][s], bb, acc[1][cf], 0, 0, 0);
                }
            }

            if (pass == 0) {
#pragma unroll
                for (int rf = 0; rf < 2; ++rf)
#pragma unroll
                    for (int cf = 0; cf < 4; ++cf)
#pragma unroll
                        for (int j = 0; j < 4; ++j)
                            vmax[rf][j] = fmaxf(vmax[rf][j], acc[rf][cf][j]);
            } else {
#pragma unroll
                for (int rf = 0; rf < 2; ++rf)
#pragma unroll
                    for (int cf = 0; cf < 4; ++cf)
#pragma unroll
                        for (int j = 0; j < 4; ++j) {
                            const float v = acc[rf][cf][j];
                            if (v >= thr[rf][j]) {
                                const int row  = r0w + rf * 16 + akg * 4 + j;
                                const int code = (ct << 6) + (cf << 4) + arow;
                                const int slot = atomicAdd(&rowcnt[row], 1);
                                if (slot < CAP) rowlist[row][slot] = (unsigned short)code;
                                else if (slot == CAP) {
                                    const int fi = atomicAdd(&nflag, 1);
                                    if (fi < 32) flagrows[fi] = row;
                                }
                            }
                        }
            }
            __syncthreads();                   // next buf staged; all waves done reading
        }
        if (pass == 0) {
            // reduce vmax across the 16 code-lanes (same rows share lane>>4)
#pragma unroll
            for (int rf = 0; rf < 2; ++rf)
#pragma unroll
                for (int j = 0; j < 4; ++j) {
                    float v = vmax[rf][j];
                    v = fmaxf(v, __shfl_xor(v, 1));
                    v = fmaxf(v, __shfl_xor(v, 2));
                    v = fmaxf(v, __shfl_xor(v, 4));
                    v = fmaxf(v, __shfl_xor(v, 8));
                    vmax[rf][j] = v;
                }
            if ((lane & 15) == 0) {
#pragma unroll
                for (int rf = 0; rf < 2; ++rf)
#pragma unroll
                    for (int j = 0; j < 4; ++j)
                        rowmaxS[r0w + rf * 16 + akg * 4 + j] = vmax[rf][j];
            }
            __syncthreads();
#pragma unroll
            for (int rf = 0; rf < 2; ++rf)
#pragma unroll
                for (int j = 0; j < 4; ++j)
                    thr[rf][j] = rowmaxS[r0w + rf * 16 + akg * 4 + j] - EPS;
        }
    }
    __syncthreads();

    // ---- exact rescore of recorded candidates (validated fmaf-chain) ----
    if (tid < 256) {
        const int cnt = rowcnt[tid];
        if (cnt <= CAP) {                      // cnt >= 1 always (argmax records itself)
            const float zs = zsumS[tid];
            const float* zrow = zb + tid;
            u64 bestk = ~0ull;
            for (int basec = 0; basec < cnt; basec += 8) {
                int codes[8];
#pragma unroll
                for (int j = 0; j < 8; ++j) {
                    const int jj = basec + j;
                    codes[j] = rowlist[tid][jj < cnt ? jj : basec];
                }
                const float* ep[8];
#pragma unroll
                for (int j = 0; j < 8; ++j) ep[j] = emb + ((size_t)(C0 + codes[j]) << 8);
                float a8[8] = {0.f, 0.f, 0.f, 0.f, 0.f, 0.f, 0.f, 0.f};
#pragma unroll 2
                for (int k4 = 0; k4 < 64; ++k4) {
                    const float zv0 = zrow[(size_t)(4 * k4 + 0) << 10];
                    const float zv1 = zrow[(size_t)(4 * k4 + 1) << 10];
                    const float zv2 = zrow[(size_t)(4 * k4 + 2) << 10];
                    const float zv3 = zrow[(size_t)(4 * k4 + 3) << 10];
                    float4 e4[8];
#pragma unroll
                    for (int j = 0; j < 8; ++j) e4[j] = *(const float4*)(ep[j] + 4 * k4);
#pragma unroll
                    for (int j = 0; j < 8; ++j) {
                        a8[j] = fmaf(zv0, e4[j].x, a8[j]);
                        a8[j] = fmaf(zv1, e4[j].y, a8[j]);
                        a8[j] = fmaf(zv2, e4[j].z, a8[j]);
                        a8[j] = fmaf(zv3, e4[j].w, a8[j]);
                    }
                }
#pragma unroll
                for (int j = 0; j < 8; ++j) {
                    if (basec + j < cnt) {
                        const float d = fmaf(-2.f, a8[j], zs);
                        const u64 key = ((u64)__float_as_uint(d) << 32)
                                      | (unsigned)(C0 + codes[j]);
                        if (key < bestk) bestk = key;
                    }
                }
            }
            ws_best[((size_t)(n0 + tid) << 1) + hv] = bestk;
        }
    }
    __syncthreads();

    // ---- overflow fallback: full exact scan for flagged rows (rare) ----
    const int nf = (nflag > 32) ? 32 : nflag;
    for (int f = 0; f < nf; ++f) {
        const int fr = flagrows[f];
        if (tid < 256) {
            const float zs = zsumS[fr];
            const float* zrow = zb + fr;
            const float* ep0 = emb + ((size_t)(C0 + (tid << 3)) << 8);
            float a8[8] = {0.f, 0.f, 0.f, 0.f, 0.f, 0.f, 0.f, 0.f};
#pragma unroll 2
            for (int k4 = 0; k4 < 64; ++k4) {
                const float zv0 = zrow[(size_t)(4 * k4 + 0) << 10];
                const float zv1 = zrow[(size_t)(4 * k4 + 1) << 10];
                const float zv2 = zrow[(size_t)(4 * k4 + 2) << 10];
                const float zv3 = zrow[(size_t)(4 * k4 + 3) << 10];
#pragma unroll
                for (int j = 0; j < 8; ++j) {
                    const float4 e4 = *(const float4*)(ep0 + (size_t)j * 256 + 4 * k4);
                    a8[j] = fmaf(zv0, e4.x, a8[j]);
                    a8[j] = fmaf(zv1, e4.y, a8[j]);
                    a8[j] = fmaf(zv2, e4.z, a8[j]);
                    a8[j] = fmaf(zv3, e4.w, a8[j]);
                }
            }
            u64 bk = ~0ull;
#pragma unroll
            for (int j = 0; j < 8; ++j) {
                const float d = fmaf(-2.f, a8[j], zs);
                const u64 key = ((u64)__float_as_uint(d) << 32)
                              | (unsigned)(C0 + (tid << 3) + j);
                if (key < bk) bk = key;
            }
            atomicMin(&flagbest[f], bk);
        }
    }
    __syncthreads();
    if (tid < nf) ws_best[((size_t)(n0 + flagrows[tid]) << 1) + hv] = flagbest[tid];
}

// ---------------------------------------------------------------------------
// K3: z_q + per-block loss partials + (merged from vq_scatter, verbatim
// logic) idx output, one-hot ones, histogram. 1024 blocks x 32 rows; emb
// rows staged in LDS (pad 257), coalesced z read / nt z_q write.
// ---------------------------------------------------------------------------
__global__ __launch_bounds__(256)
void vq_zq(const float* __restrict__ z, const float* __restrict__ emb,
           const u64* __restrict__ ws_best, float* __restrict__ out,
           int* __restrict__ counts, double* __restrict__ parts)
{
#pragma clang fp contract(off)
    __shared__ float embT[32][257];
    __shared__ int idxS[32];
    __shared__ double red[256];

    const int tid = threadIdx.x;
    const int blk = blockIdx.x;            // 0..1023
    const int b   = blk >> 5;              // batch
    const int hw0 = (blk & 31) << 5;       // 32-row chunk
    const int n0  = (b << 10) + hw0;

    if (tid < 32) {                        // merged scatter (verbatim logic)
        const int n = n0 + tid;
        u64 m = ws_best[(size_t)n * 2];
        u64 v = ws_best[(size_t)n * 2 + 1];
        if (v < m) m = v;
        const int id = (int)(m & 0xffffffffu);
        idxS[tid] = id;
        out[O_IDX + n] = (float)id;
        out[O_ENC + (size_t)n * 4096 + id] = 1.0f;
        atomicAdd(&counts[id], 1);
    }
    __syncthreads();

    {   // fill: group g stages emb row idxS[g]; 8 lanes x 8 float4 iters
        const int g = tid >> 3, l8 = tid & 7;
        const float* er = emb + (size_t)idxS[g] * 256;
#pragma unroll
        for (int it = 0; it < 8; ++it) {
            const float4 v = *(const float4*)(er + it * 32 + l8 * 4);
            const int c = it * 32 + l8 * 4;
            embT[g][c]     = v.x;
            embT[g][c + 1] = v.y;
            embT[g][c + 2] = v.z;
            embT[g][c + 3] = v.w;
        }
    }
    __syncthreads();

    const int r  = tid & 31;
    const int cq = tid >> 5;
    const size_t base = (size_t)b * 262144 + hw0 + r;
    double val = 0.0;
#pragma unroll 4
    for (int i = 0; i < 32; ++i) {
        const int c = i * 8 + cq;
        const size_t gid = base + (size_t)c * 1024;
        const float zp = z[gid];
        const float e  = embT[r][c];
        const float t  = e - zp;
        const float zq = zp + t;
        __builtin_nontemporal_store(zq, &out[O_ZQ + gid]);
        const float diff = zq - zp;
        val += (double)(diff * diff);
    }

    red[tid] = val;
    __syncthreads();
    for (int st = 128; st > 0; st >>= 1) {
        if (tid < st) red[tid] += red[tid + st];
        __syncthreads();
    }
    if (tid == 0) parts[blk] = red[0];
}

// ---------------------------------------------------------------------------
// K4: finalize loss and perplexity (1024 parts).
// ---------------------------------------------------------------------------
__global__ void vq_final(const int* __restrict__ counts,
                         const double* __restrict__ parts, float* __restrict__ out)
{
    __shared__ double red[256];
    const int t = threadIdx.x;

    double loc = 0.0;
    for (int j = t; j < NEMB; j += 256) {
        float em = (float)counts[j] * (1.0f / 32768.0f);
        float lt = em + 1e-10f;
        float lg = logf(lt);
        float pr = em * lg;
        loc += (double)pr;
    }
    red[t] = loc;
    __syncthreads();
    for (int st = 128; st > 0; st >>= 1) {
        if (t < st) red[t] += red[t + st];
        __syncthreads();
    }
    double s = red[0];
    __syncthreads();

    double q = 0.0;
    for (int j = t; j < 1024; j += 256) q += parts[j];
    red[t] = q;
    __syncthreads();
    for (int st = 128; st > 0; st >>= 1) {
        if (t < st) red[t] += red[t + st];
        __syncthreads();
    }
    if (t == 0) {
        out[O_PERP] = expf(-(float)s);
        double qm = red[0] * (1.0 / 8388608.0);
        float  qf = (float)qm;
        out[O_LOSS] = qf + 0.25f * qf;
    }
}

extern "C" void kernel_launch(void* const* d_in, const int* in_sizes, int n_in,
                              void* d_out, int out_size, void* d_ws, size_t ws_size,
                              hipStream_t stream)
{
    const float* z   = (const float*)d_in[0];
    const float* emb = (const float*)d_in[1];
    float* out = (float*)d_out;

    u64*    ws_best = (u64*)d_ws;
    int*    counts  = (int*)((char*)d_ws + 1048576);
    double* parts   = (double*)((char*)d_ws + 1064960);

    unsigned short* zbf   = (unsigned short*)((char*)d_out + 16);
    unsigned short* embsw = (unsigned short*)((char*)d_out + 16 + 16777216);

    vq_prep   <<<1152, 256, 0, stream>>>(z, emb, zbf, embsw, counts, out);
    vq_filter <<<256,  512, 0, stream>>>(z, emb, zbf, embsw, out, ws_best);
    vq_zq     <<<1024, 256, 0, stream>>>(z, emb, ws_best, out, counts, parts);
    vq_final  <<<1,    256, 0, stream>>>(counts, parts, out);
}

// Round 10
// 950.235 us; speedup vs baseline: 1.4852x; 1.2489x over previous
//
#include <hip/hip_runtime.h>

#define N_ROWS 32768
#define NEMB   4096
#define DIM    256

// output layout (flat float32)
#define O_LOSS 0
#define O_ZQ   1ull
#define O_PERP 8388609ull
#define O_ENC  8388610ull
#define O_IDX  142606338ull
// min_encodings zero region, float4-aligned interior [8388612, 142606336)
#define Z4_BEG 2097153
#define Z4_END 35651584

#define CAP    32        // per-row candidate list capacity (R7-validated)
#define EPS    1e-3f     // bf16 filter margin (needs > ~6e-4; proven passing)

typedef unsigned long long u64;
typedef __attribute__((ext_vector_type(8))) __bf16 bf16x8;
typedef __attribute__((ext_vector_type(4))) float  f32x4;

// workspace layout
// [0, 512KB)          u64 ws_best[32768][2]
// [1048576, +16KB)    int counts[4096]
// [1064960, +16KB)    double parts[2048]  (1024 used)
//
// bf16 scratch inside z_q output region (overwritten later by vq_zq):
//   zbf  : z as bf16 row-major [32768][256] (16 MB) at out+16B
//   embsw: emb bf16, 16B-chunk XOR-swizzled (chunk ^= code&7) per 512B row (2 MB)

__device__ __forceinline__ unsigned int f2bf1(float x) {
    unsigned int u = __float_as_uint(x);
    return (u + 0x7fffu + ((u >> 16) & 1u)) >> 16;
}
__device__ __forceinline__ unsigned int f2bf2(float lo, float hi) {
    return f2bf1(lo) | (f2bf1(hi) << 16);
}

// ---------------------------------------------------------------------------
// K0: one-time prep (validated, unchanged).
// ---------------------------------------------------------------------------
__global__ __launch_bounds__(256)
void vq_prep(const float* __restrict__ z, const float* __restrict__ emb,
             unsigned short* __restrict__ zbf, unsigned short* __restrict__ embsw,
             int* __restrict__ counts, float* __restrict__ out)
{
    const int tid = threadIdx.x, blk = blockIdx.x;
    if (blk < 1024) {
        __shared__ float L[32][256];
        const int b = blk >> 5, sub = blk & 31;
        const int c0 = (sub >> 2) << 5;
        const int hw0 = (sub & 3) << 8;
        const float* zp = z + (size_t)b * 262144 + hw0 + tid;
#pragma unroll 8
        for (int i = 0; i < 32; ++i)
            L[i][tid] = zp[(size_t)(c0 + i) << 10];
        __syncthreads();
        const int n = (b << 10) + hw0 + tid;
        unsigned int pk[16];
#pragma unroll
        for (int c2 = 0; c2 < 16; ++c2)
            pk[c2] = f2bf2(L[2 * c2][tid], L[2 * c2 + 1][tid]);
        uint4* dst = (uint4*)((char*)zbf + (size_t)n * 512 + (size_t)c0 * 2);
#pragma unroll
        for (int q = 0; q < 4; ++q)
            dst[q] = make_uint4(pk[4*q], pk[4*q+1], pk[4*q+2], pk[4*q+3]);
    } else {
        const int base = ((blk - 1024) << 8) + tid;
#pragma unroll
        for (int q = 0; q < 4; ++q) {
            const int ch = (base << 2) + q;
            const int code = ch >> 5, cw = ch & 31;
            const float* ep = emb + (size_t)code * 256 + cw * 8;
            float4 e0 = *(const float4*)ep;
            float4 e1 = *(const float4*)(ep + 4);
            uint4 pk = make_uint4(f2bf2(e0.x, e0.y), f2bf2(e0.z, e0.w),
                                  f2bf2(e1.x, e1.y), f2bf2(e1.z, e1.w));
            *(uint4*)((char*)embsw + (size_t)code * 512 + (size_t)((cw ^ (code & 7)) << 4)) = pk;
        }
        if (blk == 1024) {
            for (int j = tid; j < NEMB; j += 256) counts[j] = 0;
            if (tid == 0) {
                out[O_ENC] = 0.f; out[O_ENC + 1] = 0.f;
                out[(size_t)Z4_END * 4] = 0.f; out[(size_t)Z4_END * 4 + 1] = 0.f;
            }
        }
    }
}

// ---------------------------------------------------------------------------
// K1: bf16-MFMA filter + exact-fp32 rescore — VERBATIM R7 kernel (measured
// 446 us, MfmaUtil 12.5%, 3x reproduced). Two passes, lockstep __syncthreads
// double buffer, fused PLAIN-store zero-fill (L2-buffered acks; nt stores
// regressed 446->702 in R9 because the per-barrier vmcnt(0) drain then waits
// on HBM acks instead of L2 acks). 5 structural deviations failed
// (R2/R4 async, R6 retile, R8 single-pass, R9 nt+CAP16) — structure frozen.
// ---------------------------------------------------------------------------
__global__ __launch_bounds__(512, 2)
void vq_filter(const float* __restrict__ z, const float* __restrict__ emb,
               const unsigned short* __restrict__ zbf_us,
               const unsigned short* __restrict__ embsw,
               float* __restrict__ out, u64* __restrict__ ws_best)
{
#pragma clang fp contract(off)
    __shared__ __align__(16) char Bsh[65536];     // 2 x (64 codes x 256 k) bf16
    __shared__ float zsumS[256];
    __shared__ float rowmaxS[256];
    __shared__ unsigned short rowlist[256][CAP];
    __shared__ int rowcnt[256];
    __shared__ int nflag;
    __shared__ int flagrows[32];
    __shared__ u64 flagbest[32];

    const int tid = threadIdx.x;
    const int blk = blockIdx.x;
    const int rb  = blk >> 1;            // row-block 0..127 (256 rows each)
    const int hv  = blk & 1;             // code half
    const int n0  = rb << 8;
    const int C0  = hv << 11;
    const int b   = n0 >> 10;
    const int hw0 = n0 & 1023;
    const int w    = tid >> 6;
    const int lane = tid & 63;
    const int r0w  = w << 5;             // wave's 32-row base
    const int arow = lane & 15;
    const int akg  = lane >> 4;
    const float* zb = z + (size_t)b * 262144 + hw0;

    if (tid < 32) flagbest[tid] = ~0ull;
    if (tid == 0) nflag = 0;

    // ---- zsum: numpy pairwise_sum replica (verbatim numerics) ----
    if (tid < 256) {
        rowcnt[tid] = 0;
        const float* gz = zb + tid;
        float hs0, hs1;
        {
            float r[8];
#pragma unroll
            for (int j = 0; j < 8; ++j) { float v = gz[(size_t)j << 10]; r[j] = v * v; }
            for (int m = 1; m < 16; ++m)
#pragma unroll
                for (int j = 0; j < 8; ++j) {
                    float v = gz[(size_t)(8 * m + j) << 10];
                    float sq = v * v;
                    r[j] = r[j] + sq;
                }
            hs0 = ((r[0] + r[1]) + (r[2] + r[3])) + ((r[4] + r[5]) + (r[6] + r[7]));
        }
        {
            float r[8];
#pragma unroll
            for (int j = 0; j < 8; ++j) { float v = gz[(size_t)(128 + j) << 10]; r[j] = v * v; }
            for (int m = 1; m < 16; ++m)
#pragma unroll
                for (int j = 0; j < 8; ++j) {
                    float v = gz[(size_t)(128 + 8 * m + j) << 10];
                    float sq = v * v;
                    r[j] = r[j] + sq;
                }
            hs1 = ((r[0] + r[1]) + (r[2] + r[3])) + ((r[4] + r[5]) + (r[6] + r[7]));
        }
        zsumS[tid] = hs0 + hs1;
    }

    // ---- A fragments: wave's 32 rows x full K=256, bf16, in registers ----
    bf16x8 A[2][8];
#pragma unroll
    for (int rf = 0; rf < 2; ++rf)
#pragma unroll
        for (int s = 0; s < 8; ++s)
            A[rf][s] = *(const bf16x8*)((const char*)zbf_us
                        + ((size_t)(n0 + r0w + rf * 16 + arow) << 9)
                        + (size_t)((s * 32 + akg * 8) << 1));

    // B-tile staging: linear global_load_lds (source is pre-swizzled)
    auto stage = [&](int buf, int ct) {
        const char* sb = (const char*)embsw + (((size_t)(C0 + (ct << 6))) << 9)
                         + (w << 10) + (lane << 4);
        char* db = Bsh + buf * 32768 + (w << 10);
#pragma unroll
        for (int it = 0; it < 4; ++it) {
            __builtin_amdgcn_global_load_lds(
                (const __attribute__((address_space(1))) unsigned int*)(sb + it * 8192),
                (__attribute__((address_space(3))) unsigned int*)(db + it * 8192),
                16, 0, 0);
        }
    };

    float vmax[2][4];
#pragma unroll
    for (int rf = 0; rf < 2; ++rf)
#pragma unroll
        for (int j = 0; j < 4; ++j) vmax[rf][j] = -3.4e38f;
    float thr[2][4];

    const size_t zf_base = (size_t)Z4_BEG + (size_t)blk * 131072;

    for (int pass = 0; pass < 2; ++pass) {
        stage(0, 0);
        __syncthreads();                       // drains vmcnt -> buf0 ready
        for (int ct = 0; ct < 32; ++ct) {
            const int buf = ct & 1;
            if (ct < 31) stage(buf ^ 1, ct + 1);

            // fused zero-fill of min_encodings (4 coalesced float4/thread/tile)
            {
                const int iter = pass * 32 + ct;
                const size_t g = zf_base + (size_t)iter * 2048 + tid;
                const float4 zv = make_float4(0.f, 0.f, 0.f, 0.f);
#pragma unroll
                for (int q = 0; q < 4; ++q) {
                    const size_t i4 = g + (size_t)q * 512;
                    if (i4 < (size_t)Z4_END) ((float4*)out)[i4] = zv;
                }
            }

            f32x4 acc[2][4];
            const f32x4 zz = {0.f, 0.f, 0.f, 0.f};
#pragma unroll
            for (int rf = 0; rf < 2; ++rf)
#pragma unroll
                for (int cf = 0; cf < 4; ++cf) acc[rf][cf] = zz;

            const char* bufp = Bsh + buf * 32768;
#pragma unroll
            for (int s = 0; s < 8; ++s) {
#pragma unroll
                for (int cf = 0; cf < 4; ++cf) {
                    const int cl = (cf << 4) + arow;
                    const int off = (cl << 9) + (((s << 6) + (akg << 4)) ^ ((cl & 7) << 4));
                    bf16x8 bb = *(const bf16x8*)(bufp + off);
                    acc[0][cf] = __builtin_amdgcn_mfma_f32_16x16x32_bf16(A[0][s], bb, acc[0][cf], 0, 0, 0);
                    acc[1][cf] = __builtin_amdgcn_mfma_f32_16x16x32_bf16(A[1][s], bb, acc[1][cf], 0, 0, 0);
                }
            }

            if (pass == 0) {
#pragma unroll
                for (int rf = 0; rf < 2; ++rf)
#pragma unroll
                    for (int cf = 0; cf < 4; ++cf)
#pragma unroll
                        for (int j = 0; j < 4; ++j)
                            vmax[rf][j] = fmaxf(vmax[rf][j], acc[rf][cf][j]);
            } else {
#pragma unroll
                for (int rf = 0; rf < 2; ++rf)
#pragma unroll
                    for (int cf = 0; cf < 4; ++cf)
#pragma unroll
                        for (int j = 0; j < 4; ++j) {
                            const float v = acc[rf][cf][j];
                            if (v >= thr[rf][j]) {
                                const int row  = r0w + rf * 16 + akg * 4 + j;
                                const int code = (ct << 6) + (cf << 4) + arow;
                                const int slot = atomicAdd(&rowcnt[row], 1);
                                if (slot < CAP) rowlist[row][slot] = (unsigned short)code;
                                else if (slot == CAP) {
                                    const int fi = atomicAdd(&nflag, 1);
                                    if (fi < 32) flagrows[fi] = row;
                                }
                            }
                        }
            }
            __syncthreads();                   // next buf staged; all waves done reading
        }
        if (pass == 0) {
            // reduce vmax across the 16 code-lanes (same rows share lane>>4)
#pragma unroll
            for (int rf = 0; rf < 2; ++rf)
#pragma unroll
                for (int j = 0; j < 4; ++j) {
                    float v = vmax[rf][j];
                    v = fmaxf(v, __shfl_xor(v, 1));
                    v = fmaxf(v, __shfl_xor(v, 2));
                    v = fmaxf(v, __shfl_xor(v, 4));
                    v = fmaxf(v, __shfl_xor(v, 8));
                    vmax[rf][j] = v;
                }
            if ((lane & 15) == 0) {
#pragma unroll
                for (int rf = 0; rf < 2; ++rf)
#pragma unroll
                    for (int j = 0; j < 4; ++j)
                        rowmaxS[r0w + rf * 16 + akg * 4 + j] = vmax[rf][j];
            }
            __syncthreads();
#pragma unroll
            for (int rf = 0; rf < 2; ++rf)
#pragma unroll
                for (int j = 0; j < 4; ++j)
                    thr[rf][j] = rowmaxS[r0w + rf * 16 + akg * 4 + j] - EPS;
        }
    }
    __syncthreads();

    // ---- exact rescore of recorded candidates (validated fmaf-chain) ----
    if (tid < 256) {
        const int cnt = rowcnt[tid];
        if (cnt <= CAP) {                      // cnt >= 1 always (argmax records itself)
            const float zs = zsumS[tid];
            const float* zrow = zb + tid;
            u64 bestk = ~0ull;
            for (int basec = 0; basec < cnt; basec += 8) {
                int codes[8];
#pragma unroll
                for (int j = 0; j < 8; ++j) {
                    const int jj = basec + j;
                    codes[j] = rowlist[tid][jj < cnt ? jj : basec];
                }
                const float* ep[8];
#pragma unroll
                for (int j = 0; j < 8; ++j) ep[j] = emb + ((size_t)(C0 + codes[j]) << 8);
                float a8[8] = {0.f, 0.f, 0.f, 0.f, 0.f, 0.f, 0.f, 0.f};
#pragma unroll 2
                for (int k4 = 0; k4 < 64; ++k4) {
                    const float zv0 = zrow[(size_t)(4 * k4 + 0) << 10];
                    const float zv1 = zrow[(size_t)(4 * k4 + 1) << 10];
                    const float zv2 = zrow[(size_t)(4 * k4 + 2) << 10];
                    const float zv3 = zrow[(size_t)(4 * k4 + 3) << 10];
                    float4 e4[8];
#pragma unroll
                    for (int j = 0; j < 8; ++j) e4[j] = *(const float4*)(ep[j] + 4 * k4);
#pragma unroll
                    for (int j = 0; j < 8; ++j) {
                        a8[j] = fmaf(zv0, e4[j].x, a8[j]);
                        a8[j] = fmaf(zv1, e4[j].y, a8[j]);
                        a8[j] = fmaf(zv2, e4[j].z, a8[j]);
                        a8[j] = fmaf(zv3, e4[j].w, a8[j]);
                    }
                }
#pragma unroll
                for (int j = 0; j < 8; ++j) {
                    if (basec + j < cnt) {
                        const float d = fmaf(-2.f, a8[j], zs);
                        const u64 key = ((u64)__float_as_uint(d) << 32)
                                      | (unsigned)(C0 + codes[j]);
                        if (key < bestk) bestk = key;
                    }
                }
            }
            ws_best[((size_t)(n0 + tid) << 1) + hv] = bestk;
        }
    }
    __syncthreads();

    // ---- overflow fallback: full exact scan for flagged rows (rare) ----
    const int nf = (nflag > 32) ? 32 : nflag;
    for (int f = 0; f < nf; ++f) {
        const int fr = flagrows[f];
        if (tid < 256) {
            const float zs = zsumS[fr];
            const float* zrow = zb + fr;
            const float* ep0 = emb + ((size_t)(C0 + (tid << 3)) << 8);
            float a8[8] = {0.f, 0.f, 0.f, 0.f, 0.f, 0.f, 0.f, 0.f};
#pragma unroll 2
            for (int k4 = 0; k4 < 64; ++k4) {
                const float zv0 = zrow[(size_t)(4 * k4 + 0) << 10];
                const float zv1 = zrow[(size_t)(4 * k4 + 1) << 10];
                const float zv2 = zrow[(size_t)(4 * k4 + 2) << 10];
                const float zv3 = zrow[(size_t)(4 * k4 + 3) << 10];
#pragma unroll
                for (int j = 0; j < 8; ++j) {
                    const float4 e4 = *(const float4*)(ep0 + (size_t)j * 256 + 4 * k4);
                    a8[j] = fmaf(zv0, e4.x, a8[j]);
                    a8[j] = fmaf(zv1, e4.y, a8[j]);
                    a8[j] = fmaf(zv2, e4.z, a8[j]);
                    a8[j] = fmaf(zv3, e4.w, a8[j]);
                }
            }
            u64 bk = ~0ull;
#pragma unroll
            for (int j = 0; j < 8; ++j) {
                const float d = fmaf(-2.f, a8[j], zs);
                const u64 key = ((u64)__float_as_uint(d) << 32)
                              | (unsigned)(C0 + (tid << 3) + j);
                if (key < bk) bk = key;
            }
            atomicMin(&flagbest[f], bk);
        }
    }
    __syncthreads();
    if (tid < nf) ws_best[((size_t)(n0 + flagrows[tid]) << 1) + hv] = flagbest[tid];
}

// ---------------------------------------------------------------------------
// K3: z_q + per-block loss partials + merged scatter (R9-validated).
// 1024 blocks x 32 rows; emb rows staged in LDS (pad 257), coalesced z read,
// nt z_q write. zq = fl(zp + fl(e - zp)), contract off (bitwise-identical).
// ---------------------------------------------------------------------------
__global__ __launch_bounds__(256)
void vq_zq(const float* __restrict__ z, const float* __restrict__ emb,
           const u64* __restrict__ ws_best, float* __restrict__ out,
           int* __restrict__ counts, double* __restrict__ parts)
{
#pragma clang fp contract(off)
    __shared__ float embT[32][257];
    __shared__ int idxS[32];
    __shared__ double red[256];

    const int tid = threadIdx.x;
    const int blk = blockIdx.x;            // 0..1023
    const int b   = blk >> 5;              // batch
    const int hw0 = (blk & 31) << 5;       // 32-row chunk
    const int n0  = (b << 10) + hw0;

    if (tid < 32) {                        // merged scatter (verbatim logic)
        const int n = n0 + tid;
        u64 m = ws_best[(size_t)n * 2];
        u64 v = ws_best[(size_t)n * 2 + 1];
        if (v < m) m = v;
        const int id = (int)(m & 0xffffffffu);
        idxS[tid] = id;
        out[O_IDX + n] = (float)id;
        out[O_ENC + (size_t)n * 4096 + id] = 1.0f;
        atomicAdd(&counts[id], 1);
    }
    __syncthreads();

    {   // fill: group g stages emb row idxS[g]; 8 lanes x 8 float4 iters
        const int g = tid >> 3, l8 = tid & 7;
        const float* er = emb + (size_t)idxS[g] * 256;
#pragma unroll
        for (int it = 0; it < 8; ++it) {
            const float4 v = *(const float4*)(er + it * 32 + l8 * 4);
            const int c = it * 32 + l8 * 4;
            embT[g][c]     = v.x;
            embT[g][c + 1] = v.y;
            embT[g][c + 2] = v.z;
            embT[g][c + 3] = v.w;
        }
    }
    __syncthreads();

    const int r  = tid & 31;
    const int cq = tid >> 5;
    const size_t base = (size_t)b * 262144 + hw0 + r;
    double val = 0.0;
#pragma unroll 4
    for (int i = 0; i < 32; ++i) {
        const int c = i * 8 + cq;
        const size_t gid = base + (size_t)c * 1024;
        const float zp = z[gid];
        const float e  = embT[r][c];
        const float t  = e - zp;
        const float zq = zp + t;
        __builtin_nontemporal_store(zq, &out[O_ZQ + gid]);
        const float diff = zq - zp;
        val += (double)(diff * diff);
    }

    red[tid] = val;
    __syncthreads();
    for (int st = 128; st > 0; st >>= 1) {
        if (tid < st) red[tid] += red[tid + st];
        __syncthreads();
    }
    if (tid == 0) parts[blk] = red[0];
}

// ---------------------------------------------------------------------------
// K4: finalize loss and perplexity (1024 parts).
// ---------------------------------------------------------------------------
__global__ void vq_final(const int* __restrict__ counts,
                         const double* __restrict__ parts, float* __restrict__ out)
{
    __shared__ double red[256];
    const int t = threadIdx.x;

    double loc = 0.0;
    for (int j = t; j < NEMB; j += 256) {
        float em = (float)counts[j] * (1.0f / 32768.0f);
        float lt = em + 1e-10f;
        float lg = logf(lt);
        float pr = em * lg;
        loc += (double)pr;
    }
    red[t] = loc;
    __syncthreads();
    for (int st = 128; st > 0; st >>= 1) {
        if (t < st) red[t] += red[t + st];
        __syncthreads();
    }
    double s = red[0];
    __syncthreads();

    double q = 0.0;
    for (int j = t; j < 1024; j += 256) q += parts[j];
    red[t] = q;
    __syncthreads();
    for (int st = 128; st > 0; st >>= 1) {
        if (t < st) red[t] += red[t + st];
        __syncthreads();
    }
    if (t == 0) {
        out[O_PERP] = expf(-(float)s);
        double qm = red[0] * (1.0 / 8388608.0);
        float  qf = (float)qm;
        out[O_LOSS] = qf + 0.25f * qf;
    }
}

extern "C" void kernel_launch(void* const* d_in, const int* in_sizes, int n_in,
                              void* d_out, int out_size, void* d_ws, size_t ws_size,
                              hipStream_t stream)
{
    const float* z   = (const float*)d_in[0];
    const float* emb = (const float*)d_in[1];
    float* out = (float*)d_out;

    u64*    ws_best = (u64*)d_ws;
    int*    counts  = (int*)((char*)d_ws + 1048576);
    double* parts   = (double*)((char*)d_ws + 1064960);

    unsigned short* zbf   = (unsigned short*)((char*)d_out + 16);
    unsigned short* embsw = (unsigned short*)((char*)d_out + 16 + 16777216);

    vq_prep   <<<1152, 256, 0, stream>>>(z, emb, zbf, embsw, counts, out);
    vq_filter <<<256,  512, 0, stream>>>(z, emb, zbf, embsw, out, ws_best);
    vq_zq     <<<1024, 256, 0, stream>>>(z, emb, ws_best, out, counts, parts);
    vq_final  <<<1,    256, 0, stream>>>(counts, parts, out);
}

// Round 11
// 932.279 us; speedup vs baseline: 1.5138x; 1.0193x over previous
//
#include <hip/hip_runtime.h>

#define N_ROWS 32768
#define NEMB   4096
#define DIM    256

// output layout (flat float32)
#define O_LOSS 0
#define O_ZQ   1ull
#define O_PERP 8388609ull
#define O_ENC  8388610ull
#define O_IDX  142606338ull
// min_encodings zero region, float4-aligned interior [8388612, 142606336)
#define Z4_BEG 2097153
#define Z4_END 35651584

#define CAP    32        // per-row candidate list capacity (R7-validated)
#define EPS    1e-3f     // bf16 filter margin (needs > ~6e-4; proven passing)

typedef unsigned long long u64;
typedef __attribute__((ext_vector_type(8))) __bf16 bf16x8;
typedef __attribute__((ext_vector_type(4))) float  f32x4;

// 16B value, 4B alignment: z_q region starts at out+4B so float4 stores there
// are 4B-aligned only. AMD global multi-dword stores need only dword align.
struct __attribute__((packed, aligned(4))) f4u { float x, y, z, w; };

// workspace layout
// [0, 512KB)          u64 ws_best[32768][2]
// [1048576, +16KB)    int counts[4096]
// [1064960, +16KB)    double parts[2048]  (1024 used)
//
// bf16 scratch inside z_q output region (overwritten later by vq_zq):
//   embsw: emb bf16, 16B-chunk XOR-swizzled (chunk ^= code&7) per 512B row (2 MB)
//   (zbf eliminated in R11: filter converts z->bf16 inline, bitwise-same f2bf1)

__device__ __forceinline__ unsigned int f2bf1(float x) {
    unsigned int u = __float_as_uint(x);
    return (u + 0x7fffu + ((u >> 16) & 1u)) >> 16;
}
__device__ __forceinline__ unsigned int f2bf2(float lo, float hi) {
    return f2bf1(lo) | (f2bf1(hi) << 16);
}

// ---------------------------------------------------------------------------
// K0: prep, embsw only (z->zbf pass eliminated). 128 blocks.
// ---------------------------------------------------------------------------
__global__ __launch_bounds__(256)
void vq_prep(const float* __restrict__ emb, unsigned short* __restrict__ embsw,
             int* __restrict__ counts, float* __restrict__ out)
{
    const int tid = threadIdx.x, blk = blockIdx.x;
    const int base = (blk << 8) + tid;                   // 0..32767
#pragma unroll
    for (int q = 0; q < 4; ++q) {
        const int ch = (base << 2) + q;                  // 16B chunk id
        const int code = ch >> 5, cw = ch & 31;
        const float* ep = emb + (size_t)code * 256 + cw * 8;
        float4 e0 = *(const float4*)ep;
        float4 e1 = *(const float4*)(ep + 4);
        uint4 pk = make_uint4(f2bf2(e0.x, e0.y), f2bf2(e0.z, e0.w),
                              f2bf2(e1.x, e1.y), f2bf2(e1.z, e1.w));
        *(uint4*)((char*)embsw + (size_t)code * 512 + (size_t)((cw ^ (code & 7)) << 4)) = pk;
    }
    if (blk == 0) {
        for (int j = tid; j < NEMB; j += 256) counts[j] = 0;
        if (tid == 0) {
            out[O_ENC] = 0.f; out[O_ENC + 1] = 0.f;
            out[(size_t)Z4_END * 4] = 0.f; out[(size_t)Z4_END * 4 + 1] = 0.f;
        }
    }
}

// ---------------------------------------------------------------------------
// K1: bf16-MFMA filter + exact-fp32 rescore — FROZEN R7 two-pass lockstep
// schedule (5 structural deviations failed; schedule untouched). R11 change:
// A-fragments built inline from raw z with the SAME f2bf1 RNE conversion the
// old prep used -> bitwise-identical MFMA inputs -> identical candidate sets.
// One-time prologue: 128 strided scalar z loads/thread (64B-coalesced per
// 16-lane group), replacing the zbf global pass (was ~135 us).
// ---------------------------------------------------------------------------
__global__ __launch_bounds__(512, 2)
void vq_filter(const float* __restrict__ z, const float* __restrict__ emb,
               const unsigned short* __restrict__ embsw,
               float* __restrict__ out, u64* __restrict__ ws_best)
{
#pragma clang fp contract(off)
    __shared__ __align__(16) char Bsh[65536];     // 2 x (64 codes x 256 k) bf16
    __shared__ float zsumS[256];
    __shared__ float rowmaxS[256];
    __shared__ unsigned short rowlist[256][CAP];
    __shared__ int rowcnt[256];
    __shared__ int nflag;
    __shared__ int flagrows[32];
    __shared__ u64 flagbest[32];

    const int tid = threadIdx.x;
    const int blk = blockIdx.x;
    const int rb  = blk >> 1;            // row-block 0..127 (256 rows each)
    const int hv  = blk & 1;             // code half
    const int n0  = rb << 8;
    const int C0  = hv << 11;
    const int b   = n0 >> 10;
    const int hw0 = n0 & 1023;
    const int w    = tid >> 6;
    const int lane = tid & 63;
    const int r0w  = w << 5;             // wave's 32-row base
    const int arow = lane & 15;
    const int akg  = lane >> 4;
    const float* zb = z + (size_t)b * 262144 + hw0;

    if (tid < 32) flagbest[tid] = ~0ull;
    if (tid == 0) nflag = 0;

    // ---- zsum: numpy pairwise_sum replica (verbatim numerics) ----
    if (tid < 256) {
        rowcnt[tid] = 0;
        const float* gz = zb + tid;
        float hs0, hs1;
        {
            float r[8];
#pragma unroll
            for (int j = 0; j < 8; ++j) { float v = gz[(size_t)j << 10]; r[j] = v * v; }
            for (int m = 1; m < 16; ++m)
#pragma unroll
                for (int j = 0; j < 8; ++j) {
                    float v = gz[(size_t)(8 * m + j) << 10];
                    float sq = v * v;
                    r[j] = r[j] + sq;
                }
            hs0 = ((r[0] + r[1]) + (r[2] + r[3])) + ((r[4] + r[5]) + (r[6] + r[7]));
        }
        {
            float r[8];
#pragma unroll
            for (int j = 0; j < 8; ++j) { float v = gz[(size_t)(128 + j) << 10]; r[j] = v * v; }
            for (int m = 1; m < 16; ++m)
#pragma unroll
                for (int j = 0; j < 8; ++j) {
                    float v = gz[(size_t)(128 + 8 * m + j) << 10];
                    float sq = v * v;
                    r[j] = r[j] + sq;
                }
            hs1 = ((r[0] + r[1]) + (r[2] + r[3])) + ((r[4] + r[5]) + (r[6] + r[7]));
        }
        zsumS[tid] = hs0 + hs1;
    }

    // ---- A fragments: wave's 32 rows x K=256, bf16 converted inline from z.
    // Element j of A[rf][s] is c = s*32 + akg*8 + j, row r0w+rf*16+arow —
    // identical (c,row) set and identical f2bf1 rounding as the old zbf path.
    bf16x8 A[2][8];
#pragma unroll
    for (int rf = 0; rf < 2; ++rf) {
        const float* zr = zb + r0w + rf * 16 + arow;
#pragma unroll
        for (int s = 0; s < 8; ++s) {
            union { unsigned int u[4]; bf16x8 v; } cvt;
#pragma unroll
            for (int p = 0; p < 4; ++p) {
                const int c = s * 32 + akg * 8 + 2 * p;
                const float lo = zr[(size_t)c << 10];
                const float hi = zr[(size_t)(c + 1) << 10];
                cvt.u[p] = f2bf2(lo, hi);
            }
            A[rf][s] = cvt.v;
        }
    }

    // B-tile staging: linear global_load_lds (source is pre-swizzled)
    auto stage = [&](int buf, int ct) {
        const char* sb = (const char*)embsw + (((size_t)(C0 + (ct << 6))) << 9)
                         + (w << 10) + (lane << 4);
        char* db = Bsh + buf * 32768 + (w << 10);
#pragma unroll
        for (int it = 0; it < 4; ++it) {
            __builtin_amdgcn_global_load_lds(
                (const __attribute__((address_space(1))) unsigned int*)(sb + it * 8192),
                (__attribute__((address_space(3))) unsigned int*)(db + it * 8192),
                16, 0, 0);
        }
    };

    float vmax[2][4];
#pragma unroll
    for (int rf = 0; rf < 2; ++rf)
#pragma unroll
        for (int j = 0; j < 4; ++j) vmax[rf][j] = -3.4e38f;
    float thr[2][4];

    const size_t zf_base = (size_t)Z4_BEG + (size_t)blk * 131072;

    for (int pass = 0; pass < 2; ++pass) {
        stage(0, 0);
        __syncthreads();                       // drains vmcnt -> buf0 ready
        for (int ct = 0; ct < 32; ++ct) {
            const int buf = ct & 1;
            if (ct < 31) stage(buf ^ 1, ct + 1);

            // fused zero-fill of min_encodings (4 coalesced float4/thread/tile)
            {
                const int iter = pass * 32 + ct;
                const size_t g = zf_base + (size_t)iter * 2048 + tid;
                const float4 zv = make_float4(0.f, 0.f, 0.f, 0.f);
#pragma unroll
                for (int q = 0; q < 4; ++q) {
                    const size_t i4 = g + (size_t)q * 512;
                    if (i4 < (size_t)Z4_END) ((float4*)out)[i4] = zv;
                }
            }

            f32x4 acc[2][4];
            const f32x4 zz = {0.f, 0.f, 0.f, 0.f};
#pragma unroll
            for (int rf = 0; rf < 2; ++rf)
#pragma unroll
                for (int cf = 0; cf < 4; ++cf) acc[rf][cf] = zz;

            const char* bufp = Bsh + buf * 32768;
#pragma unroll
            for (int s = 0; s < 8; ++s) {
#pragma unroll
                for (int cf = 0; cf < 4; ++cf) {
                    const int cl = (cf << 4) + arow;
                    const int off = (cl << 9) + (((s << 6) + (akg << 4)) ^ ((cl & 7) << 4));
                    bf16x8 bb = *(const bf16x8*)(bufp + off);
                    acc[0][cf] = __builtin_amdgcn_mfma_f32_16x16x32_bf16(A[0][s], bb, acc[0][cf], 0, 0, 0);
                    acc[1][cf] = __builtin_amdgcn_mfma_f32_16x16x32_bf16(A[1][s], bb, acc[1][cf], 0, 0, 0);
                }
            }

            if (pass == 0) {
#pragma unroll
                for (int rf = 0; rf < 2; ++rf)
#pragma unroll
                    for (int cf = 0; cf < 4; ++cf)
#pragma unroll
                        for (int j = 0; j < 4; ++j)
                            vmax[rf][j] = fmaxf(vmax[rf][j], acc[rf][cf][j]);
            } else {
#pragma unroll
                for (int rf = 0; rf < 2; ++rf)
#pragma unroll
                    for (int cf = 0; cf < 4; ++cf)
#pragma unroll
                        for (int j = 0; j < 4; ++j) {
                            const float v = acc[rf][cf][j];
                            if (v >= thr[rf][j]) {
                                const int row  = r0w + rf * 16 + akg * 4 + j;
                                const int code = (ct << 6) + (cf << 4) + arow;
                                const int slot = atomicAdd(&rowcnt[row], 1);
                                if (slot < CAP) rowlist[row][slot] = (unsigned short)code;
                                else if (slot == CAP) {
                                    const int fi = atomicAdd(&nflag, 1);
                                    if (fi < 32) flagrows[fi] = row;
                                }
                            }
                        }
            }
            __syncthreads();                   // next buf staged; all waves done reading
        }
        if (pass == 0) {
            // reduce vmax across the 16 code-lanes (same rows share lane>>4)
#pragma unroll
            for (int rf = 0; rf < 2; ++rf)
#pragma unroll
                for (int j = 0; j < 4; ++j) {
                    float v = vmax[rf][j];
                    v = fmaxf(v, __shfl_xor(v, 1));
                    v = fmaxf(v, __shfl_xor(v, 2));
                    v = fmaxf(v, __shfl_xor(v, 4));
                    v = fmaxf(v, __shfl_xor(v, 8));
                    vmax[rf][j] = v;
                }
            if ((lane & 15) == 0) {
#pragma unroll
                for (int rf = 0; rf < 2; ++rf)
#pragma unroll
                    for (int j = 0; j < 4; ++j)
                        rowmaxS[r0w + rf * 16 + akg * 4 + j] = vmax[rf][j];
            }
            __syncthreads();
#pragma unroll
            for (int rf = 0; rf < 2; ++rf)
#pragma unroll
                for (int j = 0; j < 4; ++j)
                    thr[rf][j] = rowmaxS[r0w + rf * 16 + akg * 4 + j] - EPS;
        }
    }
    __syncthreads();

    // ---- exact rescore of recorded candidates (validated fmaf-chain) ----
    if (tid < 256) {
        const int cnt = rowcnt[tid];
        if (cnt <= CAP) {                      // cnt >= 1 always (argmax records itself)
            const float zs = zsumS[tid];
            const float* zrow = zb + tid;
            u64 bestk = ~0ull;
            for (int basec = 0; basec < cnt; basec += 8) {
                int codes[8];
#pragma unroll
                for (int j = 0; j < 8; ++j) {
                    const int jj = basec + j;
                    codes[j] = rowlist[tid][jj < cnt ? jj : basec];
                }
                const float* ep[8];
#pragma unroll
                for (int j = 0; j < 8; ++j) ep[j] = emb + ((size_t)(C0 + codes[j]) << 8);
                float a8[8] = {0.f, 0.f, 0.f, 0.f, 0.f, 0.f, 0.f, 0.f};
#pragma unroll 2
                for (int k4 = 0; k4 < 64; ++k4) {
                    const float zv0 = zrow[(size_t)(4 * k4 + 0) << 10];
                    const float zv1 = zrow[(size_t)(4 * k4 + 1) << 10];
                    const float zv2 = zrow[(size_t)(4 * k4 + 2) << 10];
                    const float zv3 = zrow[(size_t)(4 * k4 + 3) << 10];
                    float4 e4[8];
#pragma unroll
                    for (int j = 0; j < 8; ++j) e4[j] = *(const float4*)(ep[j] + 4 * k4);
#pragma unroll
                    for (int j = 0; j < 8; ++j) {
                        a8[j] = fmaf(zv0, e4[j].x, a8[j]);
                        a8[j] = fmaf(zv1, e4[j].y, a8[j]);
                        a8[j] = fmaf(zv2, e4[j].z, a8[j]);
                        a8[j] = fmaf(zv3, e4[j].w, a8[j]);
                    }
                }
#pragma unroll
                for (int j = 0; j < 8; ++j) {
                    if (basec + j < cnt) {
                        const float d = fmaf(-2.f, a8[j], zs);
                        const u64 key = ((u64)__float_as_uint(d) << 32)
                                      | (unsigned)(C0 + codes[j]);
                        if (key < bestk) bestk = key;
                    }
                }
            }
            ws_best[((size_t)(n0 + tid) << 1) + hv] = bestk;
        }
    }
    __syncthreads();

    // ---- overflow fallback: full exact scan for flagged rows (rare) ----
    const int nf = (nflag > 32) ? 32 : nflag;
    for (int f = 0; f < nf; ++f) {
        const int fr = flagrows[f];
        if (tid < 256) {
            const float zs = zsumS[fr];
            const float* zrow = zb + fr;
            const float* ep0 = emb + ((size_t)(C0 + (tid << 3)) << 8);
            float a8[8] = {0.f, 0.f, 0.f, 0.f, 0.f, 0.f, 0.f, 0.f};
#pragma unroll 2
            for (int k4 = 0; k4 < 64; ++k4) {
                const float zv0 = zrow[(size_t)(4 * k4 + 0) << 10];
                const float zv1 = zrow[(size_t)(4 * k4 + 1) << 10];
                const float zv2 = zrow[(size_t)(4 * k4 + 2) << 10];
                const float zv3 = zrow[(size_t)(4 * k4 + 3) << 10];
#pragma unroll
                for (int j = 0; j < 8; ++j) {
                    const float4 e4 = *(const float4*)(ep0 + (size_t)j * 256 + 4 * k4);
                    a8[j] = fmaf(zv0, e4.x, a8[j]);
                    a8[j] = fmaf(zv1, e4.y, a8[j]);
                    a8[j] = fmaf(zv2, e4.z, a8[j]);
                    a8[j] = fmaf(zv3, e4.w, a8[j]);
                }
            }
            u64 bk = ~0ull;
#pragma unroll
            for (int j = 0; j < 8; ++j) {
                const float d = fmaf(-2.f, a8[j], zs);
                const u64 key = ((u64)__float_as_uint(d) << 32)
                              | (unsigned)(C0 + (tid << 3) + j);
                if (key < bk) bk = key;
            }
            atomicMin(&flagbest[f], bk);
        }
    }
    __syncthreads();
    if (tid < nf) ws_best[((size_t)(n0 + flagrows[tid]) << 1) + hv] = flagbest[tid];
}

// ---------------------------------------------------------------------------
// K3: z_q + loss partials + merged scatter — R11 vectorized. 1024 blocks x
// (32 hw x 256 c). Thread (c = tid>>3, hw4 = (tid&7)*4) processes 8 float4:
// float4 z loads, float4 PLAIN z_q stores via 4B-aligned f4u (region offset
// +1 float; nt scalar stores were the R9-measured drain pathology).
// Per-element zq = fl(zp + fl(e - zp)) unchanged; double partials.
// ---------------------------------------------------------------------------
__global__ __launch_bounds__(256)
void vq_zq(const float* __restrict__ z, const float* __restrict__ emb,
           const u64* __restrict__ ws_best, float* __restrict__ out,
           int* __restrict__ counts, double* __restrict__ parts)
{
#pragma clang fp contract(off)
    __shared__ float embT[32][257];
    __shared__ int idxS[32];
    __shared__ double red[256];

    const int tid = threadIdx.x;
    const int blk = blockIdx.x;            // 0..1023
    const int b   = blk >> 5;              // batch
    const int hw0 = (blk & 31) << 5;       // 32-row chunk
    const int n0  = (b << 10) + hw0;

    if (tid < 32) {                        // merged scatter (verbatim logic)
        const int n = n0 + tid;
        u64 m = ws_best[(size_t)n * 2];
        u64 v = ws_best[(size_t)n * 2 + 1];
        if (v < m) m = v;
        const int id = (int)(m & 0xffffffffu);
        idxS[tid] = id;
        out[O_IDX + n] = (float)id;
        out[O_ENC + (size_t)n * 4096 + id] = 1.0f;
        atomicAdd(&counts[id], 1);
    }
    __syncthreads();

    {   // fill: group g stages emb row idxS[g]; 8 lanes x 8 float4 iters
        const int g = tid >> 3, l8 = tid & 7;
        const float* er = emb + (size_t)idxS[g] * 256;
#pragma unroll
        for (int it = 0; it < 8; ++it) {
            const float4 v = *(const float4*)(er + it * 32 + l8 * 4);
            const int c = it * 32 + l8 * 4;
            embT[g][c]     = v.x;
            embT[g][c + 1] = v.y;
            embT[g][c + 2] = v.z;
            embT[g][c + 3] = v.w;
        }
    }
    __syncthreads();

    const int c0t = tid >> 3;              // 0..31
    const int h4  = (tid & 7) << 2;        // 0,4,...,28
    const size_t base = (size_t)b * 262144 + hw0 + h4;
    double val = 0.0;
#pragma unroll 2
    for (int p = 0; p < 8; ++p) {
        const int c = p * 32 + c0t;
        const size_t gid = base + ((size_t)c << 10);
        const float4 zp4 = *(const float4*)(z + gid);
        const float e0 = embT[h4 + 0][c];
        const float e1 = embT[h4 + 1][c];
        const float e2 = embT[h4 + 2][c];
        const float e3 = embT[h4 + 3][c];
        const float t0 = e0 - zp4.x;  const float q0 = zp4.x + t0;
        const float t1 = e1 - zp4.y;  const float q1 = zp4.y + t1;
        const float t2 = e2 - zp4.z;  const float q2 = zp4.z + t2;
        const float t3 = e3 - zp4.w;  const float q3 = zp4.w + t3;
        f4u st; st.x = q0; st.y = q1; st.z = q2; st.w = q3;
        *(f4u*)(out + O_ZQ + gid) = st;
        const float d0 = q0 - zp4.x, d1 = q1 - zp4.y;
        const float d2 = q2 - zp4.z, d3 = q3 - zp4.w;
        val += (double)(d0 * d0) + (double)(d1 * d1)
             + (double)(d2 * d2) + (double)(d3 * d3);
    }

    red[tid] = val;
    __syncthreads();
    for (int st = 128; st > 0; st >>= 1) {
        if (tid < st) red[tid] += red[tid + st];
        __syncthreads();
    }
    if (tid == 0) parts[blk] = red[0];
}

// ---------------------------------------------------------------------------
// K4: finalize loss and perplexity (1024 parts).
// ---------------------------------------------------------------------------
__global__ void vq_final(const int* __restrict__ counts,
                         const double* __restrict__ parts, float* __restrict__ out)
{
    __shared__ double red[256];
    const int t = threadIdx.x;

    double loc = 0.0;
    for (int j = t; j < NEMB; j += 256) {
        float em = (float)counts[j] * (1.0f / 32768.0f);
        float lt = em + 1e-10f;
        float lg = logf(lt);
        float pr = em * lg;
        loc += (double)pr;
    }
    red[t] = loc;
    __syncthreads();
    for (int st = 128; st > 0; st >>= 1) {
        if (t < st) red[t] += red[t + st];
        __syncthreads();
    }
    double s = red[0];
    __syncthreads();

    double q = 0.0;
    for (int j = t; j < 1024; j += 256) q += parts[j];
    red[t] = q;
    __syncthreads();
    for (int st = 128; st > 0; st >>= 1) {
        if (t < st) red[t] += red[t + st];
        __syncthreads();
    }
    if (t == 0) {
        out[O_PERP] = expf(-(float)s);
        double qm = red[0] * (1.0 / 8388608.0);
        float  qf = (float)qm;
        out[O_LOSS] = qf + 0.25f * qf;
    }
}

extern "C" void kernel_launch(void* const* d_in, const int* in_sizes, int n_in,
                              void* d_out, int out_size, void* d_ws, size_t ws_size,
                              hipStream_t stream)
{
    const float* z   = (const float*)d_in[0];
    const float* emb = (const float*)d_in[1];
    float* out = (float*)d_out;

    u64*    ws_best = (u64*)d_ws;
    int*    counts  = (int*)((char*)d_ws + 1048576);
    double* parts   = (double*)((char*)d_ws + 1064960);

    unsigned short* embsw = (unsigned short*)((char*)d_out + 16 + 16777216);

    vq_prep   <<<128,  256, 0, stream>>>(emb, embsw, counts, out);
    vq_filter <<<256,  512, 0, stream>>>(z, emb, embsw, out, ws_best);
    vq_zq     <<<1024, 256, 0, stream>>>(z, emb, ws_best, out, counts, parts);
    vq_final  <<<1,    256, 0, stream>>>(counts, parts, out);
}